// Round 1
// baseline (186.446 us; speedup 1.0000x reference)
//
#include <hip/hip_runtime.h>

// HMaxPool2D on (32,128,128,64) f32, NHWC.
// Derived closed form of _build(128,128):
//   oh=ow=43, pooling[oi,oj] = padded (3oi+1, 3oj+1+(oi&1))
//   => in unpadded x coords the 3x3 window is centered at (3oi, 3oj+(oi&1)).
// Mask: oi even -> MASK_ODD (top/bot rows skip dc=-1)
//       oi odd  -> MASK_EVEN (top/bot rows skip dc=+1)
// max(g*mask) over 9 entries == max(0, max over the 7 active entries),
// with out-of-range (padding) reads contributing 0 (absorbed by the clamp).

constexpr int B = 32, H = 128, W = 128, C = 64;
constexpr int OH = 43, OW = 43;
constexpr int C4 = C / 4;             // 16 float4 per pixel
constexpr int NV = B * OH * OW * C4;  // 946688 float4 outputs

__global__ __launch_bounds__(256)
void hmaxpool_kernel(const float4* __restrict__ x, float4* __restrict__ out) {
    int g = blockIdx.x * 256 + threadIdx.x;
    if (g >= NV) return;

    int c4 = g & (C4 - 1);   // channel quad
    int p  = g >> 4;         // pixel index
    int oj = p % OW;
    int t  = p / OW;
    int oi = t % OH;
    int b  = t / OH;

    int par = oi & 1;
    int rx  = 3 * oi;         // center row in x coords
    int cx  = 3 * oj + par;   // center col in x coords

    float4 m = make_float4(0.f, 0.f, 0.f, 0.f);

    auto acc = [&](int r, int c) {
        if ((unsigned)r < (unsigned)H && (unsigned)c < (unsigned)W) {
            float4 v = x[((b * H + r) * W + c) * C4 + c4];
            m.x = fmaxf(m.x, v.x);
            m.y = fmaxf(m.y, v.y);
            m.z = fmaxf(m.z, v.z);
            m.w = fmaxf(m.w, v.w);
        }
    };

    // middle row: all three cols active
    acc(rx, cx - 1); acc(rx, cx); acc(rx, cx + 1);

    // top/bottom rows: two active cols
    //   par==0 (MASK_ODD): skip dc=-1 -> active {cx, cx+1}
    //   par==1 (MASK_EVEN): skip dc=+1 -> active {cx-1, cx}
    int ca = par ? (cx - 1) : cx;
    int cb = ca + 1;
    acc(rx - 1, ca); acc(rx - 1, cb);
    acc(rx + 1, ca); acc(rx + 1, cb);

    out[g] = m;
}

extern "C" void kernel_launch(void* const* d_in, const int* in_sizes, int n_in,
                              void* d_out, int out_size, void* d_ws, size_t ws_size,
                              hipStream_t stream) {
    const float4* x = (const float4*)d_in[0];
    float4* out = (float4*)d_out;
    int blocks = (NV + 255) / 256;
    hipLaunchKernelGGL(hmaxpool_kernel, dim3(blocks), dim3(256), 0, stream, x, out);
}